// Round 5
// baseline (2704.572 us; speedup 1.0000x reference)
//
#include <hip/hip_runtime.h>

// Corr1d_x: out[n,ch,h,w] = (1/C) * sum_c img1[n,c,h,w] * img2[n,c,h,w + (ch-23)]
// Shapes: img1,img2 [8,256,128,256] fp32; out [8,27,128,256] fp32.
// v5: v4 structure, fixed for spills + deeper pipeline:
//   - __launch_bounds__(256,2): ~200 VGPR budget, acc[27]x4 stays in regs.
//   - counted s_waitcnt vmcnt(8): next chunk's 4 DMA + 4 img1 loads stay in
//     flight across the current compute phase (issue-before-wait, T4).
//   - LDS reads as ds_read_b64 (volatile float2) -- measured 3.7 extra
//     conflict-cyc/instr vs 22.4 for b128 on this layout.
// Barrier-free main loop: 1024 blocks x 4 waves, each wave owns one (n,h)
// row and a 64-channel C-quarter with a private LDS double-buffer.

#define N_      8
#define C_      256
#define H_      128
#define W_      256
#define NCH     27
#define NCQ     64                   // channels per wave
#define CHUNK   4                    // c-slices per pipeline step
#define NCHUNK  (NCQ / CHUNK)        // 16
#define LROW    288                  // 24 left pad + 256 + 8 right pad
#define PADL    24
#define WLDS    (2 * CHUNK * LROW)   // floats per wave region (dbuf) = 2304
#define SMEM_FLOATS (4 * WLDS)       // 36864 B

__device__ __forceinline__ void async_cp16(const float* g, float* l) {
  __builtin_amdgcn_global_load_lds(
      (const __attribute__((address_space(1))) void*)g,
      (__attribute__((address_space(3))) void*)l,
      16, 0, 0);
}

__global__ __launch_bounds__(256, 2)
void corr1d_kernel(const float* __restrict__ img1,
                   const float* __restrict__ img2,
                   float* __restrict__ out) {
  __shared__ __align__(16) float smem[SMEM_FLOATS];

  const int tid  = threadIdx.x;
  const int wv   = tid >> 6;          // 0..3 -> C-quarter
  const int lane = tid & 63;
  const int w0   = lane << 2;         // lane owns outputs w0..w0+3

  const int nh = blockIdx.x;          // one (n,h) row per block
  const int n  = nh >> 7;
  const int h  = nh & (H_ - 1);

  float* wbase = &smem[wv * WLDS];

  // Zero ONLY the pad columns of this wave's region (payload is written
  // solely by the LDS-DMA; pads [0,24) and [280,288) stay zero forever).
  {
    const int row = lane >> 3;             // 8 rows x 32 pad floats
    const int j   = (lane & 7) << 2;       // 0,4,..,28
    const int off = (j < PADL) ? j : j + 256;
    *(float4*)(wbase + row * LROW + off) = make_float4(0.f, 0.f, 0.f, 0.f);
  }

  const size_t plane = (size_t)H_ * W_;
  const float* i1p = img1 + ((size_t)n * C_ + wv * NCQ) * plane
                          + (size_t)h * W_ + w0;
  const float* i2p = img2 + ((size_t)n * C_ + wv * NCQ) * plane
                          + (size_t)h * W_ + w0;   // lane*16B for gload_lds

  auto stage = [&](int c0, int buf) {
    #pragma unroll
    for (int r = 0; r < CHUNK; ++r)
      async_cp16(i2p + (size_t)(c0 + r) * plane,
                 wbase + (buf * CHUNK + r) * LROW + PADL);
  };

  float4 pA[CHUNK], pB[CHUNK];
  float4 acc[NCH];
  #pragma unroll
  for (int ch = 0; ch < NCH; ++ch) acc[ch] = make_float4(0.f, 0.f, 0.f, 0.f);

  stage(0, 0);
  #pragma unroll
  for (int r = 0; r < CHUNK; ++r)
    pA[r] = *(const float4*)(i1p + (size_t)r * plane);

  // body(k): issue chunk k+1 (DMA + img1->nxt), counted-wait chunk k, compute.
  auto body = [&](int k, float4 (&cur)[CHUNK], float4 (&nxt)[CHUNK], bool more) {
    const int buf = k & 1;
    if (more) {
      const int c0n = (k + 1) * CHUNK;
      stage(c0n, buf ^ 1);                 // 4 DMA into the free buffer
      #pragma unroll
      for (int r = 0; r < CHUNK; ++r)      // 4 img1 loads (next chunk)
        nxt[r] = *(const float4*)(i1p + (size_t)(c0n + r) * plane);
      // 8 newest ops (next chunk) stay in flight; chunk k fully landed.
      asm volatile("s_waitcnt vmcnt(8)" ::: "memory");
    } else {
      asm volatile("s_waitcnt vmcnt(0)" ::: "memory");
    }
    #pragma unroll
    for (int r = 0; r < CHUNK; ++r) {
      const float4 a = cur[r];
      // volatile float2: force 16x ds_read_b64 (cheaper conflicts than b128)
      const volatile float2* lrow =
          (const volatile float2*)(wbase + (buf * CHUNK + r) * LROW + w0);
      float f[32];
      #pragma unroll
      for (int q = 0; q < 16; ++q) {
        float2 t; t.x = lrow[q].x; t.y = lrow[q].y;
        f[2 * q] = t.x; f[2 * q + 1] = t.y;
      }
      #pragma unroll
      for (int ch = 0; ch < NCH; ++ch) {
        // img2[w0+j+ch-23] -> padded slot w0 + j + ch + 1 -> f[j+ch+1]
        acc[ch].x = fmaf(a.x, f[ch + 1], acc[ch].x);
        acc[ch].y = fmaf(a.y, f[ch + 2], acc[ch].y);
        acc[ch].z = fmaf(a.z, f[ch + 3], acc[ch].z);
        acc[ch].w = fmaf(a.w, f[ch + 4], acc[ch].w);
      }
    }
  };

  #pragma unroll 1
  for (int k = 0; k < NCHUNK; k += 2) {
    body(k,     pA, pB, true);                  // k <= 14 -> k+1 < 16 always
    body(k + 1, pB, pA, (k + 2) < NCHUNK);
  }

  // Combine the four C-quarters (27*64 float4 reuses staging LDS).
  float4* red = (float4*)smem;
  __syncthreads();                    // all staging reads done
  #pragma unroll 1
  for (int s = 1; s < 4; ++s) {
    if (wv == s) {
      #pragma unroll
      for (int ch = 0; ch < NCH; ++ch) red[ch * 64 + lane] = acc[ch];
    }
    __syncthreads();
    if (wv == 0) {
      #pragma unroll
      for (int ch = 0; ch < NCH; ++ch) {
        float4 t = red[ch * 64 + lane];
        acc[ch].x += t.x; acc[ch].y += t.y; acc[ch].z += t.z; acc[ch].w += t.w;
      }
    }
    __syncthreads();
  }

  if (wv == 0) {
    const float scale = 1.0f / C_;
    float* op = out + (size_t)n * NCH * plane + (size_t)h * W_ + w0;
    #pragma unroll
    for (int ch = 0; ch < NCH; ++ch) {
      float4 v = make_float4(acc[ch].x * scale, acc[ch].y * scale,
                             acc[ch].z * scale, acc[ch].w * scale);
      *(float4*)(op + (size_t)ch * plane) = v;
    }
  }
}

extern "C" void kernel_launch(void* const* d_in, const int* in_sizes, int n_in,
                              void* d_out, int out_size, void* d_ws, size_t ws_size,
                              hipStream_t stream) {
  const float* img1 = (const float*)d_in[0];
  const float* img2 = (const float*)d_in[1];
  float* out = (float*)d_out;
  corr1d_kernel<<<dim3(N_ * H_), dim3(256), 0, stream>>>(img1, img2, out);
}

// Round 6
// 754.289 us; speedup vs baseline: 3.5856x; 3.5856x over previous
//
#include <hip/hip_runtime.h>

// Corr1d_x: out[n,ch,h,w] = (1/C) * sum_c img1[n,c,h,w] * img2[n,c,h,w + (ch-23)]
// Shapes: img1,img2 [8,256,128,256] fp32; out [8,27,128,256] fp32.
// v6: 2x2 wave split to kill register pressure (the v4/v5 spill disease):
//   block = one (n,h) row, 4 independent waves = {c-half ci} x {ch-half chj}.
//   Each wave: 14 output channels x WT=4 -> acc = 56 VGPRs (vs 108 full-ch),
//   5x ds_read_b128 window/c, private LDS dbuf, barrier-free main loop with
//   issue-then-s_waitcnt vmcnt(8) (v5's counted pipeline, which was correct).
//   36.9KB LDS -> 4 blocks/CU; ~130 VGPR -> 16 waves/CU.
//   Pair waves (ci=0/1, same chj) combine partials via one LDS round.

#define N_      8
#define C_      256
#define H_      128
#define W_      256
#define NCH     27
#define NCQ     128                  // c-channels per wave (half of C)
#define CHUNK   4                    // c-slices per pipeline step
#define NCHUNK  (NCQ / CHUNK)        // 32
#define LROW    288                  // 24 left pad + 256 + 8 right pad
#define PADL    24
#define WLDS    (2 * CHUNK * LROW)   // floats per wave region (dbuf) = 2304
#define SMEM_FLOATS (4 * WLDS)       // 36864 B

__device__ __forceinline__ void async_cp16(const float* g, float* l) {
  __builtin_amdgcn_global_load_lds(
      (const __attribute__((address_space(1))) void*)g,
      (__attribute__((address_space(3))) void*)l,
      16, 0, 0);
}

__global__ __launch_bounds__(256, 3)
void corr1d_kernel(const float* __restrict__ img1,
                   const float* __restrict__ img2,
                   float* __restrict__ out) {
  __shared__ __align__(16) float smem[SMEM_FLOATS];

  const int tid  = threadIdx.x;
  const int wv   = tid >> 6;
  const int lane = tid & 63;
  const int w0   = lane << 2;         // lane owns outputs w0..w0+3
  const int ci   = wv & 1;            // c-half
  const int chj  = wv >> 1;           // ch-half: 0 -> ch 0..13, 1 -> ch 14..26
  const int a0off = chj ? 12 : 0;     // aligned window start (slot w0+a0off)

  const int nh = blockIdx.x;          // one (n,h) row per block
  const int n  = nh >> 7;
  const int h  = nh & (H_ - 1);

  float* wbase = &smem[wv * WLDS];

  // Zero ONLY the pad columns of this wave's region (payload is DMA-only;
  // pads [0,24) and [280,288) stay zero forever = shift zero-padding).
  {
    const int row = lane >> 3;             // 8 rows x 32 pad floats
    const int j   = (lane & 7) << 2;       // 0,4,..,28
    const int off = (j < PADL) ? j : j + 256;
    *(float4*)(wbase + row * LROW + off) = make_float4(0.f, 0.f, 0.f, 0.f);
  }

  const size_t plane = (size_t)H_ * W_;
  const float* i1p = img1 + ((size_t)n * C_ + ci * NCQ) * plane
                          + (size_t)h * W_ + w0;
  const float* i2p = img2 + ((size_t)n * C_ + ci * NCQ) * plane
                          + (size_t)h * W_ + w0;   // lane*16B for gload_lds

  auto stage = [&](int c0, int buf) {
    #pragma unroll
    for (int r = 0; r < CHUNK; ++r)
      async_cp16(i2p + (size_t)(c0 + r) * plane,
                 wbase + (buf * CHUNK + r) * LROW + PADL);
  };

  float4 pA[CHUNK], pB[CHUNK];
  float4 acc[14];                     // chj=1's acc[13] is waste, never stored
  #pragma unroll
  for (int ch = 0; ch < 14; ++ch) acc[ch] = make_float4(0.f, 0.f, 0.f, 0.f);

  stage(0, 0);
  #pragma unroll
  for (int r = 0; r < CHUNK; ++r)
    pA[r] = *(const float4*)(i1p + (size_t)r * plane);

  // body(k): issue chunk k+1 (4 DMA + 4 img1), counted-wait chunk k, compute.
  auto body = [&](int k, float4 (&cur)[CHUNK], float4 (&nxt)[CHUNK], bool more) {
    const int buf = k & 1;
    if (more) {
      const int c0n = (k + 1) * CHUNK;
      stage(c0n, buf ^ 1);
      #pragma unroll
      for (int r = 0; r < CHUNK; ++r)
        nxt[r] = *(const float4*)(i1p + (size_t)(c0n + r) * plane);
      asm volatile("s_waitcnt vmcnt(8)" ::: "memory");  // chunk k landed
    } else {
      asm volatile("s_waitcnt vmcnt(0)" ::: "memory");
    }
    #pragma unroll
    for (int r = 0; r < CHUNK; ++r) {
      const float4 a = cur[r];
      const float4* lrow =
          (const float4*)(wbase + (buf * CHUNK + r) * LROW + w0 + a0off);
      float f[20];
      #pragma unroll
      for (int q = 0; q < 5; ++q) {        // 5x ds_read_b128, 16B lane stride
        float4 t = lrow[q];
        f[4*q] = t.x; f[4*q+1] = t.y; f[4*q+2] = t.z; f[4*q+3] = t.w;
      }
      // thread needs img2[w0+j+ch-23] = padded slot w0+j+ch+1, ch = chj*14+ch'
      // f index = j + ch + 1 - a0off:
      //   chj=0: f[ch'+1+j]  (max 17) ; chj=1: f[ch'+3+j]  (max 19)
      const int fo = chj ? 3 : 1;
      #pragma unroll
      for (int c2 = 0; c2 < 14; ++c2) {
        acc[c2].x = fmaf(a.x, f[c2 + fo    ], acc[c2].x);
        acc[c2].y = fmaf(a.y, f[c2 + fo + 1], acc[c2].y);
        acc[c2].z = fmaf(a.z, f[c2 + fo + 2], acc[c2].z);
        acc[c2].w = fmaf(a.w, f[c2 + fo + 3], acc[c2].w);
      }
    }
  };

  #pragma unroll 1
  for (int k = 0; k < NCHUNK; k += 2) {
    body(k,     pA, pB, true);                    // k <= 30 -> k+1 < 32
    body(k + 1, pB, pA, (k + 2) < NCHUNK);
  }

  // Combine c-halves: ci=1 writes partials, ci=0 adds + stores.
  float4* red = (float4*)smem;        // [chj*14 + ch][lane], 28.7KB
  __syncthreads();                    // all staging reads done
  if (ci == 1) {
    #pragma unroll
    for (int ch = 0; ch < 14; ++ch)
      red[(chj * 14 + ch) * 64 + lane] = acc[ch];
  }
  __syncthreads();
  if (ci == 0) {
    const float scale = 1.0f / C_;
    const int nst = chj ? 13 : 14;    // chj=1: ch 14..26 only
    float* op = out + ((size_t)n * NCH + chj * 14) * plane + (size_t)h * W_ + w0;
    for (int ch = 0; ch < nst; ++ch) {
      float4 t = red[(chj * 14 + ch) * 64 + lane];
      float4 v = make_float4((acc[ch].x + t.x) * scale,
                             (acc[ch].y + t.y) * scale,
                             (acc[ch].z + t.z) * scale,
                             (acc[ch].w + t.w) * scale);
      *(float4*)(op + (size_t)ch * plane) = v;
    }
  }
}

extern "C" void kernel_launch(void* const* d_in, const int* in_sizes, int n_in,
                              void* d_out, int out_size, void* d_ws, size_t ws_size,
                              hipStream_t stream) {
  const float* img1 = (const float*)d_in[0];
  const float* img2 = (const float*)d_in[1];
  float* out = (float*)d_out;
  corr1d_kernel<<<dim3(N_ * H_), dim3(256), 0, stream>>>(img1, img2, out);
}

// Round 7
// 369.260 us; speedup vs baseline: 7.3243x; 2.0427x over previous
//
#include <hip/hip_runtime.h>
#include <type_traits>

// Corr1d_x: out[n,ch,h,w] = (1/C) * sum_c img1[n,c,h,w] * img2[n,c,h,w + (ch-23)]
// Shapes: img1,img2 [8,256,128,256] fp32; out [8,27,128,256] fp32.
// v7 = v6 with the scratch disease fixed (rule #20):
//   - window index offset FO and alignment A0 are compile-time (generic
//     lambda on integral_constant<CHJ>), so f[20] stays in VGPRs.
//   - store loops fully unrolled with compile-time trip counts, so acc[14]
//     stays in VGPRs.
// Block = one (n,h) row, 4 independent waves = {c-half ci} x {ch-half chj};
// private LDS double-buffer per wave, barrier-free main loop, counted
// s_waitcnt vmcnt(8) pipeline. 36.9KB LDS; ~140 VGPR -> 12 waves/CU.

#define N_      8
#define C_      256
#define H_      128
#define W_      256
#define NCH     27
#define NCQ     128                  // c-channels per wave (half of C)
#define CHUNK   4                    // c-slices per pipeline step
#define NCHUNK  (NCQ / CHUNK)        // 32
#define LROW    288                  // 24 left pad + 256 + 8 right pad
#define PADL    24
#define WLDS    (2 * CHUNK * LROW)   // floats per wave region (dbuf) = 2304
#define SMEM_FLOATS (4 * WLDS)       // 36864 B

__device__ __forceinline__ void async_cp16(const float* g, float* l) {
  __builtin_amdgcn_global_load_lds(
      (const __attribute__((address_space(1))) void*)g,
      (__attribute__((address_space(3))) void*)l,
      16, 0, 0);
}

__global__ __launch_bounds__(256, 3)
void corr1d_kernel(const float* __restrict__ img1,
                   const float* __restrict__ img2,
                   float* __restrict__ out) {
  __shared__ __align__(16) float smem[SMEM_FLOATS];

  const int tid  = threadIdx.x;
  const int wv   = tid >> 6;
  const int lane = tid & 63;
  const int w0   = lane << 2;         // lane owns outputs w0..w0+3
  const int ci   = wv & 1;            // c-half
  const int chj  = wv >> 1;           // ch-half: 0 -> ch 0..13, 1 -> ch 14..26

  const int nh = blockIdx.x;          // one (n,h) row per block
  const int n  = nh >> 7;
  const int h  = nh & (H_ - 1);

  float* wbase = &smem[wv * WLDS];

  // Zero ONLY the pad columns of this wave's region (payload is DMA-only;
  // pads [0,24) and [280,288) stay zero forever = shift zero-padding).
  {
    const int row = lane >> 3;             // 8 rows x 32 pad floats
    const int j   = (lane & 7) << 2;       // 0,4,..,28
    const int off = (j < PADL) ? j : j + 256;
    *(float4*)(wbase + row * LROW + off) = make_float4(0.f, 0.f, 0.f, 0.f);
  }

  const size_t plane = (size_t)H_ * W_;
  const float* i1p = img1 + ((size_t)n * C_ + ci * NCQ) * plane
                          + (size_t)h * W_ + w0;
  const float* i2p = img2 + ((size_t)n * C_ + ci * NCQ) * plane
                          + (size_t)h * W_ + w0;   // lane*16B for gload_lds

  auto stage = [&](int c0, int buf) {
    #pragma unroll
    for (int r = 0; r < CHUNK; ++r)
      async_cp16(i2p + (size_t)(c0 + r) * plane,
                 wbase + (buf * CHUNK + r) * LROW + PADL);
  };

  float4 acc[14];                     // chj=1: acc[13] is waste, never stored
  #pragma unroll
  for (int ch = 0; ch < 14; ++ch) acc[ch] = make_float4(0.f, 0.f, 0.f, 0.f);

  // Entire pipeline instantiated per chj so FO/A0 are compile-time and all
  // f[] indices are constants (rule #20: no runtime-indexed register arrays).
  auto run = [&](auto CHJC) {
    constexpr int CHJ = decltype(CHJC)::value;
    constexpr int FO  = CHJ ? 3 : 1;   // f index = c2 + FO + j
    constexpr int A0  = CHJ ? 12 : 0;  // window start slot (16B aligned)

    float4 pA[CHUNK], pB[CHUNK];
    stage(0, 0);
    #pragma unroll
    for (int r = 0; r < CHUNK; ++r)
      pA[r] = *(const float4*)(i1p + (size_t)r * plane);

    auto body = [&](int k, float4 (&cur)[CHUNK], float4 (&nxt)[CHUNK],
                    bool more) {
      const int buf = k & 1;
      if (more) {
        const int c0n = (k + 1) * CHUNK;
        stage(c0n, buf ^ 1);                 // 4 DMA into the free buffer
        #pragma unroll
        for (int r = 0; r < CHUNK; ++r)      // 4 img1 loads (next chunk)
          nxt[r] = *(const float4*)(i1p + (size_t)(c0n + r) * plane);
        asm volatile("s_waitcnt vmcnt(8)" ::: "memory");  // chunk k landed
      } else {
        asm volatile("s_waitcnt vmcnt(0)" ::: "memory");
      }
      #pragma unroll
      for (int r = 0; r < CHUNK; ++r) {
        const float4 a = cur[r];
        const float4* lrow =
            (const float4*)(wbase + (buf * CHUNK + r) * LROW + w0 + A0);
        float f[20];
        #pragma unroll
        for (int q = 0; q < 5; ++q) {        // 5x ds_read_b128
          float4 t = lrow[q];
          f[4*q] = t.x; f[4*q+1] = t.y; f[4*q+2] = t.z; f[4*q+3] = t.w;
        }
        // img2[w0+j+ch-23] -> padded slot w0+j+ch+1; ch = CHJ*14 + c2
        // f index = j + ch + 1 - A0 = j + c2 + FO  (compile-time)
        #pragma unroll
        for (int c2 = 0; c2 < 14; ++c2) {
          acc[c2].x = fmaf(a.x, f[c2 + FO    ], acc[c2].x);
          acc[c2].y = fmaf(a.y, f[c2 + FO + 1], acc[c2].y);
          acc[c2].z = fmaf(a.z, f[c2 + FO + 2], acc[c2].z);
          acc[c2].w = fmaf(a.w, f[c2 + FO + 3], acc[c2].w);
        }
      }
    };

    #pragma unroll 1
    for (int k = 0; k < NCHUNK; k += 2) {
      body(k,     pA, pB, true);                    // k <= 30 -> k+1 < 32
      body(k + 1, pB, pA, (k + 2) < NCHUNK);
    }
  };
  if (chj == 0) run(std::integral_constant<int, 0>{});
  else          run(std::integral_constant<int, 1>{});

  // Combine c-halves: ci=1 writes partials, ci=0 adds + stores.
  float4* red = (float4*)smem;        // [chj*14 + ch][lane] float4, 28.7KB
  __syncthreads();                    // all staging reads done
  if (ci == 1) {
    #pragma unroll
    for (int ch = 0; ch < 14; ++ch)
      red[(chj * 14 + ch) * 64 + lane] = acc[ch];
  }
  __syncthreads();
  if (ci == 0) {
    const float scale = 1.0f / C_;
    float* op = out + ((size_t)n * NCH + chj * 14) * plane
                    + (size_t)h * W_ + w0;
    if (chj == 0) {
      #pragma unroll
      for (int ch = 0; ch < 14; ++ch) {
        float4 t = red[ch * 64 + lane];
        float4 v = make_float4((acc[ch].x + t.x) * scale,
                               (acc[ch].y + t.y) * scale,
                               (acc[ch].z + t.z) * scale,
                               (acc[ch].w + t.w) * scale);
        *(float4*)(op + (size_t)ch * plane) = v;
      }
    } else {
      #pragma unroll
      for (int ch = 0; ch < 13; ++ch) {   // global ch 14..26
        float4 t = red[(14 + ch) * 64 + lane];
        float4 v = make_float4((acc[ch].x + t.x) * scale,
                               (acc[ch].y + t.y) * scale,
                               (acc[ch].z + t.z) * scale,
                               (acc[ch].w + t.w) * scale);
        *(float4*)(op + (size_t)ch * plane) = v;
      }
    }
  }
}

extern "C" void kernel_launch(void* const* d_in, const int* in_sizes, int n_in,
                              void* d_out, int out_size, void* d_ws, size_t ws_size,
                              hipStream_t stream) {
  const float* img1 = (const float*)d_in[0];
  const float* img2 = (const float*)d_in[1];
  float* out = (float*)d_out;
  corr1d_kernel<<<dim3(N_ * H_), dim3(256), 0, stream>>>(img1, img2, out);
}